// Round 2
// baseline (275.088 us; speedup 1.0000x reference)
//
#include <hip/hip_runtime.h>
#include <hip/hip_bf16.h>
#include <math.h>

// Problem dims
constexpr int BD = 32;
constexpr int SD = 512;
constexpr int RD = 49;
constexpr int HD = 768;
constexpr int MT = BD * SD;    // 16384 text rows
constexpr int MI = BD * RD;    // 1568 img rows
constexpr int NP = 12;         // 6 n-blocks x 2 wave-columns partials per row
constexpr int MBT = MT / 128;  // 128 text m-blocks
constexpr int MBI = 13;        // img m-blocks (1664 padded rows; OOB-safe, see launcher)
constexpr int NWG = (MBT + MBI) * 6;  // 846 gemm blocks
constexpr int NT = HD / 32;    // 24 K-tiles

typedef __bf16 bf16;
typedef __bf16 bf16x4 __attribute__((ext_vector_type(4)));
typedef __bf16 bf16x8 __attribute__((ext_vector_type(8)));
typedef float f32x4 __attribute__((ext_vector_type(4)));

#define GLOAD_LDS16(g, l) __builtin_amdgcn_global_load_lds( \
    (__attribute__((address_space(1))) void*)(g),           \
    (__attribute__((address_space(3))) void*)(l), 16, 0, 0)
#define BAR() __builtin_amdgcn_s_barrier()
#define SCHED_FENCE() __builtin_amdgcn_sched_barrier(0)
#define WAITV(n) asm volatile("s_waitcnt vmcnt(" #n ")" ::: "memory")

__device__ __forceinline__ float fast_tanh(float x) {
    const float e = __expf(2.f * x);
    return 1.f - 2.f / (e + 1.f);
}

// ---------------------------------------------------------------------------
// prep_text: text fp32 -> text_bf (bf16) AND s_txt[row] = text[row,:].v_f
// ---------------------------------------------------------------------------
__global__ __launch_bounds__(256) void prep_text(
    const float* __restrict__ text, const float* __restrict__ v_f,
    bf16* __restrict__ text_bf, float* __restrict__ s_txt)
{
    const int row = blockIdx.x * 4 + (threadIdx.x >> 6);
    const int lane = threadIdx.x & 63;
    const float* tr = text + (size_t)row * HD;
    bf16* tb = text_bf + (size_t)row * HD;
    float acc = 0.f;
    #pragma unroll
    for (int c = 0; c < 3; ++c) {
        const int o = c * 256 + lane * 4;
        const f32x4 x = *(const f32x4*)(tr + o);
        const f32x4 v = *(const f32x4*)(v_f + o);
        bf16x4 b; b[0] = (bf16)x[0]; b[1] = (bf16)x[1]; b[2] = (bf16)x[2]; b[3] = (bf16)x[3];
        *(bf16x4*)(tb + o) = b;
        acc += x[0] * v[0] + x[1] * v[1] + x[2] * v[2] + x[3] * v[3];
    }
    for (int off = 32; off; off >>= 1) acc += __shfl_xor(acc, off);
    if (lane == 0) s_txt[row] = acc;
}

// ---------------------------------------------------------------------------
// prep_misc: fused vf_vm (385 blk) + conv_img (588 blk) + transpose_w (288 blk)
// ---------------------------------------------------------------------------
__global__ __launch_bounds__(256) void prep_misc(
    const float* __restrict__ ft_w, const float* __restrict__ fm_w,
    const float* __restrict__ fm_b, const float* __restrict__ fg_w,
    float* __restrict__ v_f, float* __restrict__ v_m, float* __restrict__ c_m,
    const float* __restrict__ img, bf16* __restrict__ img_bf,
    const float* __restrict__ t2_w, const float* __restrict__ i1_w,
    bf16* __restrict__ wt_t, bf16* __restrict__ wt_i)
{
    __shared__ float tile[64][65];
    const int bid = blockIdx.x;
    if (bid < 385) {
        const int idx = bid * 4 + (threadIdx.x >> 6);
        const int lane = threadIdx.x & 63;
        const float* row; const float* vecp; float* outp;
        if (idx < HD)            { row = ft_w + (size_t)idx * HD;        vecp = fg_w;      outp = v_f + idx; }
        else if (idx < 2 * HD)   { row = fm_w + (size_t)(idx - HD) * HD; vecp = fg_w + HD; outp = v_m + (idx - HD); }
        else if (idx == 2 * HD)  { row = fm_b;                           vecp = fg_w + HD; outp = c_m; }
        else return;
        float acc = 0.f;
        #pragma unroll
        for (int i = 0; i < HD / 64; ++i) acc += row[lane + 64 * i] * vecp[lane + 64 * i];
        for (int off = 32; off; off >>= 1) acc += __shfl_xor(acc, off);
        if (lane == 0) *outp = acc;
    } else if (bid < 385 + 588) {
        const int i = (bid - 385) * 256 + threadIdx.x;
        const int n8 = BD * RD * HD / 8;
        if (i >= n8) return;
        const size_t o = (size_t)i * 8;
        const f32x4 x0 = *(const f32x4*)(img + o);
        const f32x4 x1 = *(const f32x4*)(img + o + 4);
        bf16x8 b;
        b[0]=(bf16)x0[0]; b[1]=(bf16)x0[1]; b[2]=(bf16)x0[2]; b[3]=(bf16)x0[3];
        b[4]=(bf16)x1[0]; b[5]=(bf16)x1[1]; b[6]=(bf16)x1[2]; b[7]=(bf16)x1[3];
        *(bf16x8*)(img_bf + o) = b;
    } else {
        const int idx2 = bid - (385 + 588);
        const int z = idx2 / 144, rem = idx2 % 144;
        const int bx = rem % 12, by = rem / 12;
        const float* W = z ? i1_w : t2_w;
        bf16* Wt = z ? wt_i : wt_t;
        const int k0 = bx * 64, n0 = by * 64;
        const int t = threadIdx.x;
        const int rb = t >> 6, c = t & 63;
        #pragma unroll
        for (int i = 0; i < 16; ++i) {
            const int r = rb + i * 4;
            tile[r][c] = W[(size_t)(k0 + r) * HD + n0 + c];
        }
        __syncthreads();
        #pragma unroll
        for (int i = 0; i < 16; ++i) {
            const int r = rb + i * 4;
            Wt[(size_t)(n0 + r) * HD + k0 + c] = (bf16)tile[c][r];
        }
    }
}

// ---------------------------------------------------------------------------
// gemm2: merged score GEMMs. 128x128 tile, BK=32, 3-slot LDS ring, depth-2
// prefetch with counted vmcnt (never 0 in steady state), conflict-free chunked
// LDS layout [chunk16rows][kquad][row][8], XCD-bijective block swizzle.
// part[row][nb*2 + wavecol] = sum_{64-col slice} tanh((A@W)[row,n]) * vec[n]
// ---------------------------------------------------------------------------
__global__ __launch_bounds__(256) void gemm2(
    const bf16* __restrict__ Atext, const bf16* __restrict__ WtT,
    const float* __restrict__ vecT, float* __restrict__ partT,
    const bf16* __restrict__ Aimg, const bf16* __restrict__ WtI,
    const float* __restrict__ vecI, float* __restrict__ partI)
{
    __shared__ __align__(16) bf16 As[3 * 4096];   // 3 slots x (8 chunks x 512) = 24KB
    __shared__ __align__(16) bf16 Bs[3 * 4096];

    // bijective XCD swizzle (m204): each XCD gets a contiguous o-range
    const int bid = blockIdx.x;
    const int q = NWG / 8, r = NWG % 8;
    const int xcd = bid % 8, idx = bid / 8;
    const int o = (xcd < r ? xcd * (q + 1) : r * (q + 1) + (xcd - r) * q) + idx;
    const int mb = o / 6, nb = o % 6;

    const bool isT = mb < MBT;
    const bf16* A    = isT ? Atext : Aimg;
    const bf16* Wt   = isT ? WtT : WtI;
    const float* vec = isT ? vecT : vecI;
    float* part      = isT ? partT : partI;
    const int m0 = (isT ? mb : mb - MBT) * 128;
    const int n0 = nb * 128;

    const int t = threadIdx.x;
    const int w = t >> 6, lane = t & 63;
    const int quad = lane >> 4, l16 = lane & 15;
    const int wm2 = (w >> 1) * 64, wn2 = (w & 1) * 64;

    // staging: chunk c = 16 rows x 32 k, LDS order [kquad][row][8].
    // lane -> (row = lane&15, kquad = lane>>4); LDS dest linear (+lane*16B).
    const bf16* Ag = A  + (size_t)(m0 + w * 32 + l16) * HD + quad * 8;
    const bf16* Bg = Wt + (size_t)(n0 + w * 32 + l16) * HD + quad * 8;

    f32x4 acc[4][4] = {};

#define STAGE(tt, ss) {                                       \
    const int ko = (tt) * 32;                                 \
    bf16* a0 = As + (ss) * 4096 + (2 * w) * 512;              \
    bf16* b0 = Bs + (ss) * 4096 + (2 * w) * 512;              \
    GLOAD_LDS16(Ag + ko, a0);                                 \
    GLOAD_LDS16(Ag + (size_t)16 * HD + ko, a0 + 512);         \
    GLOAD_LDS16(Bg + ko, b0);                                 \
    GLOAD_LDS16(Bg + (size_t)16 * HD + ko, b0 + 512);         \
}

#define COMPUTE(ss) {                                                   \
    const bf16* Asl = As + (ss) * 4096;                                 \
    const bf16* Bsl = Bs + (ss) * 4096;                                 \
    bf16x8 af[4], bg4[4];                                               \
    _Pragma("unroll")                                                   \
    for (int f = 0; f < 4; ++f) {                                       \
        af[f]  = *(const bf16x8*)(Asl + (wm2 / 16 + f) * 512 + lane * 8); \
        bg4[f] = *(const bf16x8*)(Bsl + (wn2 / 16 + f) * 512 + lane * 8); \
    }                                                                   \
    _Pragma("unroll")                                                   \
    for (int fi = 0; fi < 4; ++fi)                                      \
        _Pragma("unroll")                                               \
        for (int fj = 0; fj < 4; ++fj)                                  \
            acc[fi][fj] = __builtin_amdgcn_mfma_f32_16x16x32_bf16(af[fi], bg4[fj], acc[fi][fj], 0, 0, 0); \
}

    // prologue: stage tiles 0 and 1
    STAGE(0, 0);
    STAGE(1, 1);

    // steady state: stage t+2, wait tile t (keep 8 in flight), compute t
    for (int tt = 0; tt < NT - 2; ++tt) {
        const int s2 = (tt + 2) % 3;
        STAGE(tt + 2, s2);
        WAITV(8);
        BAR();           // tile tt fully staged by all waves
        SCHED_FENCE();
        COMPUTE(tt % 3);
        SCHED_FENCE();
        BAR();           // all waves done reading slot tt%3 (restaged next iter)
    }
    // tail: tiles NT-2, NT-1
    WAITV(4);
    BAR();
    SCHED_FENCE();
    COMPUTE((NT - 2) % 3);
    SCHED_FENCE();
    WAITV(0);
    BAR();
    SCHED_FENCE();
    COMPUTE((NT - 1) % 3);

#undef STAGE
#undef COMPUTE

    // epilogue: C/D layout col=l16, row=quad*4+reg
    float vv[4];
    #pragma unroll
    for (int fj = 0; fj < 4; ++fj) vv[fj] = vec[n0 + wn2 + fj * 16 + l16];

    #pragma unroll
    for (int fi = 0; fi < 4; ++fi) {
        #pragma unroll
        for (int reg = 0; reg < 4; ++reg) {
            float p = 0.f;
            #pragma unroll
            for (int fj = 0; fj < 4; ++fj)
                p += fast_tanh(acc[fi][fj][reg]) * vv[fj];
            p += __shfl_xor(p, 1);
            p += __shfl_xor(p, 2);
            p += __shfl_xor(p, 4);
            p += __shfl_xor(p, 8);
            if (l16 == 0) {
                const int row = m0 + wm2 + fi * 16 + quad * 4 + reg;
                part[(size_t)row * NP + nb * 2 + (w & 1)] = p;
            }
        }
    }
}

// ---------------------------------------------------------------------------
// red_soft: fused partial-reduce + softmax.
// blocks 0..31: text batch b (S=512); blocks 32..63: img batch b (R=49)
// ---------------------------------------------------------------------------
__global__ __launch_bounds__(256) void red_soft(
    const float* __restrict__ k_part, const float* __restrict__ i_part,
    float* __restrict__ k_sc, float* __restrict__ i_sc)
{
    __shared__ float red[4];
    if (blockIdx.x < BD) {
        const int b = blockIdx.x, t = threadIdx.x;
        const float* p0 = k_part + ((size_t)b * SD + t) * NP;
        const float* p1 = k_part + ((size_t)b * SD + 256 + t) * NP;
        float x0 = 0.f, x1 = 0.f;
        #pragma unroll
        for (int j = 0; j < 3; ++j) {
            const f32x4 a = *(const f32x4*)(p0 + j * 4);
            const f32x4 c = *(const f32x4*)(p1 + j * 4);
            x0 += a[0] + a[1] + a[2] + a[3];
            x1 += c[0] + c[1] + c[2] + c[3];
        }
        float m = fmaxf(x0, x1);
        for (int off = 32; off; off >>= 1) m = fmaxf(m, __shfl_xor(m, off));
        if ((t & 63) == 0) red[t >> 6] = m;
        __syncthreads();
        m = fmaxf(fmaxf(red[0], red[1]), fmaxf(red[2], red[3]));
        const float e0 = expf(x0 - m), e1 = expf(x1 - m);
        float s = e0 + e1;
        for (int off = 32; off; off >>= 1) s += __shfl_xor(s, off);
        __syncthreads();
        if ((t & 63) == 0) red[t >> 6] = s;
        __syncthreads();
        s = red[0] + red[1] + red[2] + red[3];
        k_sc[b * SD + t] = e0 / s;
        k_sc[b * SD + 256 + t] = e1 / s;
    } else {
        const int b = blockIdx.x - BD, l = threadIdx.x;
        if (l < 64) {
            float x = -1e30f;
            if (l < RD) {
                const float* p = i_part + ((size_t)(b * RD + l)) * NP;
                float s0 = 0.f;
                #pragma unroll
                for (int j = 0; j < 3; ++j) {
                    const f32x4 a = *(const f32x4*)(p + j * 4);
                    s0 += a[0] + a[1] + a[2] + a[3];
                }
                x = s0;
            }
            float m = x;
            for (int off = 32; off; off >>= 1) m = fmaxf(m, __shfl_xor(m, off));
            float e = (l < RD) ? expf(x - m) : 0.f;
            float s = e;
            for (int off = 32; off; off >>= 1) s += __shfl_xor(s, off);
            if (l < RD) i_sc[b * RD + l] = e / s;
        }
    }
}

// ---------------------------------------------------------------------------
// wsum_both: blocks [0,96): aimg[b,h] = sum_j P1[b,j]*img[b,j,h]  (J=49 fp32)
//            blocks [96,480): ws_part for atxt (bf16 text, j-split 4-way)
// ---------------------------------------------------------------------------
__global__ __launch_bounds__(256) void wsum_both(
    const float* __restrict__ P1, const float* __restrict__ img,
    float* __restrict__ aimg,
    const float* __restrict__ P2, const bf16* __restrict__ text_bf,
    float* __restrict__ ws_part)
{
    __shared__ float Ps[SD];
    const int bid = blockIdx.x;
    if (bid < 96) {
        const int b = bid & 31, hy = bid >> 5;
        const int h = hy * 256 + threadIdx.x;
        for (int j = threadIdx.x; j < RD; j += 256) Ps[j] = P1[b * RD + j];
        __syncthreads();
        float acc = 0.f;
        const float* Xb = img + (size_t)b * RD * HD + h;
        for (int j = 0; j < RD; ++j) acc += Ps[j] * Xb[(size_t)j * HD];
        aimg[b * HD + h] = acc;
    } else {
        const int idx = bid - 96;
        const int q = idx / 96, rem = idx % 96;
        const int b = rem & 31, hy = rem >> 5;
        const int h = hy * 256 + threadIdx.x;
        if (threadIdx.x < 128) Ps[threadIdx.x] = P2[b * SD + q * 128 + threadIdx.x];
        __syncthreads();
        float acc = 0.f;
        const bf16* Xb = text_bf + (size_t)b * SD * HD + (size_t)(q * 128) * HD + h;
        #pragma unroll 8
        for (int j = 0; j < 128; ++j) acc += Ps[j] * (float)Xb[(size_t)j * HD];
        ws_part[((size_t)(b * 4 + q)) * HD + h] = acc;
    }
}

// ---------------------------------------------------------------------------
// ni/nt GEMV; which==1 folds the ws_part 4-way reduce
// ---------------------------------------------------------------------------
__global__ __launch_bounds__(256) void ni_nt_kernel(
    const float* __restrict__ aimg, const float* __restrict__ ws_part,
    const float* __restrict__ gi_w, const float* __restrict__ gi_b,
    const float* __restrict__ gt_w, const float* __restrict__ gt_b,
    float* __restrict__ ni, float* __restrict__ nt)
{
    const int b = blockIdx.x, n0 = blockIdx.y * 64, which = blockIdx.z;
    const float* W = which ? gt_w : gi_w;
    const float* bias = which ? gt_b : gi_b;
    float* Y = which ? nt : ni;

    __shared__ float Xs[HD];
    __shared__ float partial[4][64];
    const int t = threadIdx.x;
    if (which) {
        for (int h = t; h < HD; h += 256)
            Xs[h] = ws_part[((size_t)(b * 4 + 0)) * HD + h] + ws_part[((size_t)(b * 4 + 1)) * HD + h]
                  + ws_part[((size_t)(b * 4 + 2)) * HD + h] + ws_part[((size_t)(b * 4 + 3)) * HD + h];
    } else {
        for (int h = t; h < HD; h += 256) Xs[h] = aimg[b * HD + h];
    }
    __syncthreads();
    const int n = n0 + (t & 63), kq = t >> 6;
    float acc = 0.f;
    const float* Wp = W + (size_t)(kq * 192) * HD + n;
    #pragma unroll 8
    for (int h = 0; h < 192; ++h) acc += Xs[kq * 192 + h] * Wp[(size_t)h * HD];
    partial[kq][t & 63] = acc;
    __syncthreads();
    if (t < 64) {
        const float s = partial[0][t] + partial[1][t] + partial[2][t] + partial[3][t];
        Y[b * HD + n0 + t] = tanhf(s + bias[n0 + t]);
    }
}

// per-batch: gate g, mm row, s_mm scalar
__global__ __launch_bounds__(256) void gate_mix(
    const float* __restrict__ ni, const float* __restrict__ nt,
    const float* __restrict__ gg_w, const float* __restrict__ gg_b,
    const float* __restrict__ v_m, const float* __restrict__ c_m,
    const float* __restrict__ fg_b,
    float* __restrict__ mm, float* __restrict__ s_mm)
{
    const int b = blockIdx.x, t = threadIdx.x;
    __shared__ float red[4];
    __shared__ float gsh;
    float acc = 0.f;
    for (int n = t; n < HD; n += 256)
        acc += ni[b * HD + n] * gg_w[n] + nt[b * HD + n] * gg_w[HD + n];
    for (int off = 32; off; off >>= 1) acc += __shfl_xor(acc, off);
    if ((t & 63) == 0) red[t >> 6] = acc;
    __syncthreads();
    if (t == 0) gsh = 1.f / (1.f + expf(-(red[0] + red[1] + red[2] + red[3] + gg_b[0])));
    __syncthreads();
    const float g = gsh;
    float a2 = 0.f;
    for (int n = t; n < HD; n += 256) {
        const float m = g * ni[b * HD + n] + (1.f - g) * nt[b * HD + n];
        mm[b * HD + n] = m;
        a2 += m * v_m[n];
    }
    for (int off = 32; off; off >>= 1) a2 += __shfl_xor(a2, off);
    __syncthreads();
    if ((t & 63) == 0) red[t >> 6] = a2;
    __syncthreads();
    if (t == 0) s_mm[b] = red[0] + red[1] + red[2] + red[3] + *c_m + fg_b[0];
}

// T = tanh(mm @ fr_w + fr_b): grid (BD, HD/64)
__global__ __launch_bounds__(256) void T_kernel(
    const float* __restrict__ mm, const float* __restrict__ fr_w,
    const float* __restrict__ fr_b, float* __restrict__ T)
{
    const int b = blockIdx.x, n0 = blockIdx.y * 64;
    __shared__ float Xs[HD];
    __shared__ float partial[4][64];
    const int t = threadIdx.x;
    for (int h = t; h < HD; h += 256) Xs[h] = mm[b * HD + h];
    __syncthreads();
    const int n = n0 + (t & 63), kq = t >> 6;
    float acc = 0.f;
    const float* Wp = fr_w + (size_t)(kq * 192) * HD + n;
    #pragma unroll 8
    for (int h = 0; h < 192; ++h) acc += Xs[kq * 192 + h] * Wp[(size_t)h * HD];
    partial[kq][t & 63] = acc;
    __syncthreads();
    if (t < 64) {
        const float s = partial[0][t] + partial[1][t] + partial[2][t] + partial[3][t];
        T[b * HD + n0 + t] = tanhf(s + fr_b[n0 + t]);
    }
}

// out[b,s,h] = sigmoid(s_txt[b,s] + s_mm[b]) * T[b,h]  (reads ws only)
__global__ __launch_bounds__(256) void out_kernel(const float* __restrict__ s_txt,
                                                  const float* __restrict__ s_mm,
                                                  const float* __restrict__ T,
                                                  float* __restrict__ out) {
    const size_t idx = ((size_t)blockIdx.x * 256 + threadIdx.x) * 4;
    const int h = (int)(idx % HD);
    const int bs = (int)(idx / HD);
    const int b = bs >> 9;
    float f = s_txt[bs] + s_mm[b];
    f = 1.f / (1.f + expf(-f));
    const float* Tp = T + b * HD + h;
    f32x4 o;
    o[0] = f * Tp[0]; o[1] = f * Tp[1]; o[2] = f * Tp[2]; o[3] = f * Tp[3];
    *(f32x4*)(out + idx) = o;
}

// ---------------------------------------------------------------------------
extern "C" void kernel_launch(void* const* d_in, const int* in_sizes, int n_in,
                              void* d_out, int out_size, void* d_ws, size_t ws_size,
                              hipStream_t stream) {
    const float* text = (const float*)d_in[0];
    const float* img  = (const float*)d_in[1];
    const float* i1_w = (const float*)d_in[4];
    const float* a1_w = (const float*)d_in[5];
    const float* t2_w = (const float*)d_in[7];
    const float* a2_w = (const float*)d_in[10];
    const float* gt_w = (const float*)d_in[12];
    const float* gt_b = (const float*)d_in[13];
    const float* gi_w = (const float*)d_in[14];
    const float* gi_b = (const float*)d_in[15];
    const float* gg_w = (const float*)d_in[16];
    const float* gg_b = (const float*)d_in[17];
    const float* ft_w = (const float*)d_in[18];
    const float* fm_w = (const float*)d_in[19];
    const float* fm_b = (const float*)d_in[20];
    const float* fg_w = (const float*)d_in[21];
    const float* fg_b = (const float*)d_in[22];
    const float* fr_w = (const float*)d_in[23];
    const float* fr_b = (const float*)d_in[24];
    float* out = (float*)d_out;

    // ---- scratch inside d_out (all uses precede out_kernel) ----
    float* sc_ = out;
    float* i_part  = sc_;                 // 1664*12 = 19968 (cap 38400)
    float* k_part  = sc_ + 38400;         // 16384*12 = 196608 (cap 393216)
    float* i_sc    = sc_ + 431616;        // 1568
    float* k_sc    = sc_ + 433216;        // 16384
    float* aimg    = sc_ + 449600;        // 24576
    float* v_f     = sc_ + 498752;        // 768
    float* v_m     = sc_ + 499520;        // 768
    float* c_m     = sc_ + 500288;        // 1 (+pad)
    float* ws_part = sc_ + 500352;        // 98304
    float* ni      = sc_ + 598656;        // 24576
    float* nt      = sc_ + 623232;        // 24576
    float* mm      = sc_ + 647808;        // 24576
    bf16* text_bf  = (bf16*)(sc_ + 672384);    // 12.58M bf16
    bf16* img_bf   = (bf16*)(sc_ + 6963840);   // 1204224 bf16
    bf16* wt_t     = (bf16*)(sc_ + 7565952);   // 589824 bf16 (also absorbs img OOB reads)
    bf16* wt_i     = (bf16*)(sc_ + 7860864);   // 589824 bf16 (ends 8155776 < 12.58M)

    // ---- ws holds only what out_kernel reads ----
    float* ws    = (float*)d_ws;
    float* s_txt = ws;                    // 16384
    float* s_mm  = ws + 16384;            // 32 (+pad)
    float* T     = ws + 16448;            // 24576

    // 0. fused prep: rank-1 collapses + img->bf16 + weight transposes
    prep_misc<<<dim3(385 + 588 + 288), dim3(256), 0, stream>>>(
        ft_w, fm_w, fm_b, fg_w, v_f, v_m, c_m, img, img_bf, t2_w, i1_w, wt_t, wt_i);
    // 0b. text fp32 -> bf16 + s_txt (needs v_f)
    prep_text<<<dim3(MT / 4), dim3(256), 0, stream>>>(text, v_f, text_bf, s_txt);
    // 1/2. merged score GEMMs (pipelined) + fused reduce+softmax
    gemm2<<<dim3(NWG), dim3(256), 0, stream>>>(
        text_bf, wt_t, a2_w + HD, k_part, img_bf, wt_i, a1_w + HD, i_part);
    red_soft<<<dim3(2 * BD), dim3(256), 0, stream>>>(k_part, i_part, k_sc, i_sc);
    // 6/7. attended rows (s-independent -> one row per batch)
    wsum_both<<<dim3(96 + 384), dim3(256), 0, stream>>>(
        i_sc, img, aimg, k_sc, text_bf, ws_part);
    // 8. GMF (ni_nt folds the ws_part reduce)
    ni_nt_kernel<<<dim3(BD, HD / 64, 2), dim3(256), 0, stream>>>(
        aimg, ws_part, gi_w, gi_b, gt_w, gt_b, ni, nt);
    gate_mix<<<dim3(BD), dim3(256), 0, stream>>>(
        ni, nt, gg_w, gg_b, v_m, c_m, fg_b, mm, s_mm);
    T_kernel<<<dim3(BD, HD / 64), dim3(256), 0, stream>>>(mm, fr_w, fr_b, T);
    // 9. output (reads ws only; overwrites all of d_out)
    out_kernel<<<dim3((MT * HD / 4) / 256), dim3(256), 0, stream>>>(s_txt, s_mm, T, out);
}

// Round 3
// 266.454 us; speedup vs baseline: 1.0324x; 1.0324x over previous
//
#include <hip/hip_runtime.h>
#include <hip/hip_bf16.h>
#include <math.h>

// Problem dims
constexpr int BD = 32;
constexpr int SD = 512;
constexpr int RD = 49;
constexpr int HD = 768;
constexpr int MT = BD * SD;    // 16384 text rows
constexpr int MI = BD * RD;    // 1568 img rows
constexpr int NP = 12;         // 6 n-blocks x 2 wave-columns partials per row
constexpr int MBT = MT / 128;  // 128 text m-blocks
constexpr int MBI = 13;        // img m-blocks (1664 padded rows; OOB-safe, see launcher)
constexpr int NWG = (MBT + MBI) * 6;  // 846 gemm blocks
constexpr int NT2 = HD / 64;   // 12 K-steps (BK=64)

typedef __bf16 bf16;
typedef __bf16 bf16x4 __attribute__((ext_vector_type(4)));
typedef __bf16 bf16x8 __attribute__((ext_vector_type(8)));
typedef float f32x4 __attribute__((ext_vector_type(4)));

#define GLOAD_LDS16(g, l) __builtin_amdgcn_global_load_lds( \
    (__attribute__((address_space(1))) void*)(g),           \
    (__attribute__((address_space(3))) void*)(l), 16, 0, 0)

__device__ __forceinline__ float fast_tanh(float x) {
    const float e = __expf(2.f * x);
    return 1.f - 2.f / (e + 1.f);
}

// ---------------------------------------------------------------------------
// prep_text: text fp32 -> text_bf (bf16) AND s_txt[row] = text[row,:].v_f
// ---------------------------------------------------------------------------
__global__ __launch_bounds__(256) void prep_text(
    const float* __restrict__ text, const float* __restrict__ v_f,
    bf16* __restrict__ text_bf, float* __restrict__ s_txt)
{
    const int row = blockIdx.x * 4 + (threadIdx.x >> 6);
    const int lane = threadIdx.x & 63;
    const float* tr = text + (size_t)row * HD;
    bf16* tb = text_bf + (size_t)row * HD;
    float acc = 0.f;
    #pragma unroll
    for (int c = 0; c < 3; ++c) {
        const int o = c * 256 + lane * 4;
        const f32x4 x = *(const f32x4*)(tr + o);
        const f32x4 v = *(const f32x4*)(v_f + o);
        bf16x4 b; b[0] = (bf16)x[0]; b[1] = (bf16)x[1]; b[2] = (bf16)x[2]; b[3] = (bf16)x[3];
        *(bf16x4*)(tb + o) = b;
        acc += x[0] * v[0] + x[1] * v[1] + x[2] * v[2] + x[3] * v[3];
    }
    for (int off = 32; off; off >>= 1) acc += __shfl_xor(acc, off);
    if (lane == 0) s_txt[row] = acc;
}

// ---------------------------------------------------------------------------
// prep_misc: fused vf_vm (385 blk) + conv_img (588 blk) + transpose_w (288 blk)
// ---------------------------------------------------------------------------
__global__ __launch_bounds__(256) void prep_misc(
    const float* __restrict__ ft_w, const float* __restrict__ fm_w,
    const float* __restrict__ fm_b, const float* __restrict__ fg_w,
    float* __restrict__ v_f, float* __restrict__ v_m, float* __restrict__ c_m,
    const float* __restrict__ img, bf16* __restrict__ img_bf,
    const float* __restrict__ t2_w, const float* __restrict__ i1_w,
    bf16* __restrict__ wt_t, bf16* __restrict__ wt_i)
{
    __shared__ float tile[64][65];
    const int bid = blockIdx.x;
    if (bid < 385) {
        const int idx = bid * 4 + (threadIdx.x >> 6);
        const int lane = threadIdx.x & 63;
        const float* row; const float* vecp; float* outp;
        if (idx < HD)            { row = ft_w + (size_t)idx * HD;        vecp = fg_w;      outp = v_f + idx; }
        else if (idx < 2 * HD)   { row = fm_w + (size_t)(idx - HD) * HD; vecp = fg_w + HD; outp = v_m + (idx - HD); }
        else if (idx == 2 * HD)  { row = fm_b;                           vecp = fg_w + HD; outp = c_m; }
        else return;
        float acc = 0.f;
        #pragma unroll
        for (int i = 0; i < HD / 64; ++i) acc += row[lane + 64 * i] * vecp[lane + 64 * i];
        for (int off = 32; off; off >>= 1) acc += __shfl_xor(acc, off);
        if (lane == 0) *outp = acc;
    } else if (bid < 385 + 588) {
        const int i = (bid - 385) * 256 + threadIdx.x;
        const int n8 = BD * RD * HD / 8;
        if (i >= n8) return;
        const size_t o = (size_t)i * 8;
        const f32x4 x0 = *(const f32x4*)(img + o);
        const f32x4 x1 = *(const f32x4*)(img + o + 4);
        bf16x8 b;
        b[0]=(bf16)x0[0]; b[1]=(bf16)x0[1]; b[2]=(bf16)x0[2]; b[3]=(bf16)x0[3];
        b[4]=(bf16)x1[0]; b[5]=(bf16)x1[1]; b[6]=(bf16)x1[2]; b[7]=(bf16)x1[3];
        *(bf16x8*)(img_bf + o) = b;
    } else {
        const int idx2 = bid - (385 + 588);
        const int z = idx2 / 144, rem = idx2 % 144;
        const int bx = rem % 12, by = rem / 12;
        const float* W = z ? i1_w : t2_w;
        bf16* Wt = z ? wt_i : wt_t;
        const int k0 = bx * 64, n0 = by * 64;
        const int t = threadIdx.x;
        const int rb = t >> 6, c = t & 63;
        #pragma unroll
        for (int i = 0; i < 16; ++i) {
            const int r = rb + i * 4;
            tile[r][c] = W[(size_t)(k0 + r) * HD + n0 + c];
        }
        __syncthreads();
        #pragma unroll
        for (int i = 0; i < 16; ++i) {
            const int r = rb + i * 4;
            Wt[(size_t)(n0 + r) * HD + k0 + c] = (bf16)tile[c][r];
        }
    }
}

// ---------------------------------------------------------------------------
// gemm2: merged score GEMMs. 128x128 tile, BK=64, single-buffered LDS (32KB),
// simple __syncthreads loop (proven m97-family structure), conflict-free
// chunked LDS layout [half][rowchunk][kquad][row][8], XCD-bijective swizzle.
// 32 MFMA per wave per barrier pair.
// part[row][nb*2 + wavecol] = sum_{64-col slice} tanh((A@W)[row,n]) * vec[n]
// ---------------------------------------------------------------------------
__global__ __launch_bounds__(256, 4) void gemm2(
    const bf16* __restrict__ Atext, const bf16* __restrict__ WtT,
    const float* __restrict__ vecT, float* __restrict__ partT,
    const bf16* __restrict__ Aimg, const bf16* __restrict__ WtI,
    const float* __restrict__ vecI, float* __restrict__ partI)
{
    __shared__ __align__(16) bf16 As[16 * 512];   // 16KB: piece (h*8+rc)*512, [kq][row16][8]
    __shared__ __align__(16) bf16 Bs[16 * 512];

    // bijective XCD swizzle (m204): each XCD gets a contiguous o-range
    const int bid = blockIdx.x;
    const int q = NWG / 8, r = NWG % 8;
    const int xcd = bid % 8, sidx = bid / 8;
    const int o = (xcd < r ? xcd * (q + 1) : r * (q + 1) + (xcd - r) * q) + sidx;
    const int mb = o / 6, nb = o % 6;

    const bool isT = mb < MBT;
    const bf16* A    = isT ? Atext : Aimg;
    const bf16* Wt   = isT ? WtT : WtI;
    const float* vec = isT ? vecT : vecI;
    float* part      = isT ? partT : partI;
    const int m0 = (isT ? mb : mb - MBT) * 128;
    const int n0 = nb * 128;

    const int t = threadIdx.x;
    const int w = t >> 6, lane = t & 63;
    const int quad = lane >> 4, l16 = lane & 15;
    const int wm2 = (w >> 1) * 64, wn2 = (w & 1) * 64;

    // per-lane global src for staging piece (rc, h): row = m0 + rc*16 + l16,
    // col = kk + h*32 + quad*8. LDS dest wave-uniform + lane*16B (linear).
    const bf16* Ag = A  + (size_t)(m0 + l16) * HD + quad * 8;
    const bf16* Bg = Wt + (size_t)(n0 + l16) * HD + quad * 8;

    f32x4 acc[4][4] = {};

    for (int tt = 0; tt < NT2; ++tt) {
        const int kk = tt * 64;
        // stage: wave w stages row-chunks {2w, 2w+1} x halves {0,1}, A and B
        #pragma unroll
        for (int h = 0; h < 2; ++h) {
            #pragma unroll
            for (int j = 0; j < 2; ++j) {
                const int rc = 2 * w + j;
                GLOAD_LDS16(Ag + (size_t)rc * 16 * HD + kk + h * 32, As + (h * 8 + rc) * 512);
                GLOAD_LDS16(Bg + (size_t)rc * 16 * HD + kk + h * 32, Bs + (h * 8 + rc) * 512);
            }
        }
        __syncthreads();   // drains vmcnt(0): tiles staged by all waves

        #pragma unroll
        for (int h = 0; h < 2; ++h) {
            bf16x8 af[4], bg4[4];
            #pragma unroll
            for (int f = 0; f < 4; ++f) {
                af[f]  = *(const bf16x8*)(As + (h * 8 + wm2 / 16 + f) * 512 + lane * 8);
                bg4[f] = *(const bf16x8*)(Bs + (h * 8 + wn2 / 16 + f) * 512 + lane * 8);
            }
            #pragma unroll
            for (int fi = 0; fi < 4; ++fi)
                #pragma unroll
                for (int fj = 0; fj < 4; ++fj)
                    acc[fi][fj] = __builtin_amdgcn_mfma_f32_16x16x32_bf16(af[fi], bg4[fj], acc[fi][fj], 0, 0, 0);
        }
        __syncthreads();   // protect LDS before next stage
    }

    // epilogue: C/D layout col=l16, row=quad*4+reg
    float vv[4];
    #pragma unroll
    for (int fj = 0; fj < 4; ++fj) vv[fj] = vec[n0 + wn2 + fj * 16 + l16];

    #pragma unroll
    for (int fi = 0; fi < 4; ++fi) {
        #pragma unroll
        for (int reg = 0; reg < 4; ++reg) {
            float p = 0.f;
            #pragma unroll
            for (int fj = 0; fj < 4; ++fj)
                p += fast_tanh(acc[fi][fj][reg]) * vv[fj];
            p += __shfl_xor(p, 1);
            p += __shfl_xor(p, 2);
            p += __shfl_xor(p, 4);
            p += __shfl_xor(p, 8);
            if (l16 == 0) {
                const int row = m0 + wm2 + fi * 16 + quad * 4 + reg;
                part[(size_t)row * NP + nb * 2 + (w & 1)] = p;
            }
        }
    }
}

// ---------------------------------------------------------------------------
// red_soft: fused partial-reduce + softmax.
// blocks 0..31: text batch b (S=512); blocks 32..63: img batch b (R=49)
// ---------------------------------------------------------------------------
__global__ __launch_bounds__(256) void red_soft(
    const float* __restrict__ k_part, const float* __restrict__ i_part,
    float* __restrict__ k_sc, float* __restrict__ i_sc)
{
    __shared__ float red[4];
    if (blockIdx.x < BD) {
        const int b = blockIdx.x, t = threadIdx.x;
        const float* p0 = k_part + ((size_t)b * SD + t) * NP;
        const float* p1 = k_part + ((size_t)b * SD + 256 + t) * NP;
        float x0 = 0.f, x1 = 0.f;
        #pragma unroll
        for (int j = 0; j < 3; ++j) {
            const f32x4 a = *(const f32x4*)(p0 + j * 4);
            const f32x4 c = *(const f32x4*)(p1 + j * 4);
            x0 += a[0] + a[1] + a[2] + a[3];
            x1 += c[0] + c[1] + c[2] + c[3];
        }
        float m = fmaxf(x0, x1);
        for (int off = 32; off; off >>= 1) m = fmaxf(m, __shfl_xor(m, off));
        if ((t & 63) == 0) red[t >> 6] = m;
        __syncthreads();
        m = fmaxf(fmaxf(red[0], red[1]), fmaxf(red[2], red[3]));
        const float e0 = expf(x0 - m), e1 = expf(x1 - m);
        float s = e0 + e1;
        for (int off = 32; off; off >>= 1) s += __shfl_xor(s, off);
        __syncthreads();
        if ((t & 63) == 0) red[t >> 6] = s;
        __syncthreads();
        s = red[0] + red[1] + red[2] + red[3];
        k_sc[b * SD + t] = e0 / s;
        k_sc[b * SD + 256 + t] = e1 / s;
    } else {
        const int b = blockIdx.x - BD, l = threadIdx.x;
        if (l < 64) {
            float x = -1e30f;
            if (l < RD) {
                const float* p = i_part + ((size_t)(b * RD + l)) * NP;
                float s0 = 0.f;
                #pragma unroll
                for (int j = 0; j < 3; ++j) {
                    const f32x4 a = *(const f32x4*)(p + j * 4);
                    s0 += a[0] + a[1] + a[2] + a[3];
                }
                x = s0;
            }
            float m = x;
            for (int off = 32; off; off >>= 1) m = fmaxf(m, __shfl_xor(m, off));
            float e = (l < RD) ? expf(x - m) : 0.f;
            float s = e;
            for (int off = 32; off; off >>= 1) s += __shfl_xor(s, off);
            if (l < RD) i_sc[b * RD + l] = e / s;
        }
    }
}

// ---------------------------------------------------------------------------
// wsum_both: blocks [0,96): aimg[b,h] = sum_j P1[b,j]*img[b,j,h]  (J=49 fp32)
//            blocks [96,480): ws_part for atxt (bf16 text, j-split 4-way)
// ---------------------------------------------------------------------------
__global__ __launch_bounds__(256) void wsum_both(
    const float* __restrict__ P1, const float* __restrict__ img,
    float* __restrict__ aimg,
    const float* __restrict__ P2, const bf16* __restrict__ text_bf,
    float* __restrict__ ws_part)
{
    __shared__ float Ps[SD];
    const int bid = blockIdx.x;
    if (bid < 96) {
        const int b = bid & 31, hy = bid >> 5;
        const int h = hy * 256 + threadIdx.x;
        for (int j = threadIdx.x; j < RD; j += 256) Ps[j] = P1[b * RD + j];
        __syncthreads();
        float acc = 0.f;
        const float* Xb = img + (size_t)b * RD * HD + h;
        for (int j = 0; j < RD; ++j) acc += Ps[j] * Xb[(size_t)j * HD];
        aimg[b * HD + h] = acc;
    } else {
        const int idx = bid - 96;
        const int q = idx / 96, rem = idx % 96;
        const int b = rem & 31, hy = rem >> 5;
        const int h = hy * 256 + threadIdx.x;
        if (threadIdx.x < 128) Ps[threadIdx.x] = P2[b * SD + q * 128 + threadIdx.x];
        __syncthreads();
        float acc = 0.f;
        const bf16* Xb = text_bf + (size_t)b * SD * HD + (size_t)(q * 128) * HD + h;
        #pragma unroll 8
        for (int j = 0; j < 128; ++j) acc += Ps[j] * (float)Xb[(size_t)j * HD];
        ws_part[((size_t)(b * 4 + q)) * HD + h] = acc;
    }
}

// ---------------------------------------------------------------------------
// ni/nt GEMV; which==1 folds the ws_part 4-way reduce
// ---------------------------------------------------------------------------
__global__ __launch_bounds__(256) void ni_nt_kernel(
    const float* __restrict__ aimg, const float* __restrict__ ws_part,
    const float* __restrict__ gi_w, const float* __restrict__ gi_b,
    const float* __restrict__ gt_w, const float* __restrict__ gt_b,
    float* __restrict__ ni, float* __restrict__ nt)
{
    const int b = blockIdx.x, n0 = blockIdx.y * 64, which = blockIdx.z;
    const float* W = which ? gt_w : gi_w;
    const float* bias = which ? gt_b : gi_b;
    float* Y = which ? nt : ni;

    __shared__ float Xs[HD];
    __shared__ float partial[4][64];
    const int t = threadIdx.x;
    if (which) {
        for (int h = t; h < HD; h += 256)
            Xs[h] = ws_part[((size_t)(b * 4 + 0)) * HD + h] + ws_part[((size_t)(b * 4 + 1)) * HD + h]
                  + ws_part[((size_t)(b * 4 + 2)) * HD + h] + ws_part[((size_t)(b * 4 + 3)) * HD + h];
    } else {
        for (int h = t; h < HD; h += 256) Xs[h] = aimg[b * HD + h];
    }
    __syncthreads();
    const int n = n0 + (t & 63), kq = t >> 6;
    float acc = 0.f;
    const float* Wp = W + (size_t)(kq * 192) * HD + n;
    #pragma unroll 8
    for (int h = 0; h < 192; ++h) acc += Xs[kq * 192 + h] * Wp[(size_t)h * HD];
    partial[kq][t & 63] = acc;
    __syncthreads();
    if (t < 64) {
        const float s = partial[0][t] + partial[1][t] + partial[2][t] + partial[3][t];
        Y[b * HD + n0 + t] = tanhf(s + bias[n0 + t]);
    }
}

// ---------------------------------------------------------------------------
// gateT: fused gate_mix + T_kernel. grid (BD, 12).
// Each block redundantly computes the (cheap) gate + mm row in LDS, then its
// 64-col slice of T = tanh(mm @ fr_w + fr_b). Block y==0 also writes s_mm.
// ---------------------------------------------------------------------------
__global__ __launch_bounds__(256) void gateT(
    const float* __restrict__ ni, const float* __restrict__ nt,
    const float* __restrict__ gg_w, const float* __restrict__ gg_b,
    const float* __restrict__ v_m, const float* __restrict__ c_m,
    const float* __restrict__ fg_b,
    const float* __restrict__ fr_w, const float* __restrict__ fr_b,
    float* __restrict__ T, float* __restrict__ s_mm)
{
    const int b = blockIdx.x, n0 = blockIdx.y * 64, t = threadIdx.x;
    __shared__ float Ni[HD], Nt[HD], Mm[HD];
    __shared__ float partial[4][64];
    __shared__ float red[4];
    __shared__ float gsh;

    float acc = 0.f;
    for (int n = t; n < HD; n += 256) {
        const float vi = ni[b * HD + n], vt = nt[b * HD + n];
        Ni[n] = vi; Nt[n] = vt;
        acc += vi * gg_w[n] + vt * gg_w[HD + n];
    }
    for (int off = 32; off; off >>= 1) acc += __shfl_xor(acc, off);
    if ((t & 63) == 0) red[t >> 6] = acc;
    __syncthreads();
    if (t == 0) gsh = 1.f / (1.f + expf(-(red[0] + red[1] + red[2] + red[3] + gg_b[0])));
    __syncthreads();
    const float g = gsh;
    float a2 = 0.f;
    for (int n = t; n < HD; n += 256) {
        const float m = g * Ni[n] + (1.f - g) * Nt[n];
        Mm[n] = m;
        a2 += m * v_m[n];
    }
    __syncthreads();
    // T slice
    const int n = n0 + (t & 63), kq = t >> 6;
    float tacc = 0.f;
    const float* Wp = fr_w + (size_t)(kq * 192) * HD + n;
    #pragma unroll 8
    for (int h = 0; h < 192; ++h) tacc += Mm[kq * 192 + h] * Wp[(size_t)h * HD];
    partial[kq][t & 63] = tacc;
    if (blockIdx.y == 0) {
        for (int off = 32; off; off >>= 1) a2 += __shfl_xor(a2, off);
        __syncthreads();
        if ((t & 63) == 0) red[t >> 6] = a2;
        __syncthreads();
        if (t == 0) s_mm[b] = red[0] + red[1] + red[2] + red[3] + *c_m + fg_b[0];
    } else {
        __syncthreads();
    }
    __syncthreads();
    if (t < 64) {
        const float s = partial[0][t] + partial[1][t] + partial[2][t] + partial[3][t];
        T[b * HD + n0 + t] = tanhf(s + fr_b[n0 + t]);
    }
}

// out[b,s,h] = sigmoid(s_txt[b,s] + s_mm[b]) * T[b,h]  (reads ws only)
__global__ __launch_bounds__(256) void out_kernel(const float* __restrict__ s_txt,
                                                  const float* __restrict__ s_mm,
                                                  const float* __restrict__ T,
                                                  float* __restrict__ out) {
    const size_t idx = ((size_t)blockIdx.x * 256 + threadIdx.x) * 4;
    const int h = (int)(idx % HD);
    const int bs = (int)(idx / HD);
    const int b = bs >> 9;
    float f = s_txt[bs] + s_mm[b];
    f = 1.f / (1.f + expf(-f));
    const float* Tp = T + b * HD + h;
    f32x4 o;
    o[0] = f * Tp[0]; o[1] = f * Tp[1]; o[2] = f * Tp[2]; o[3] = f * Tp[3];
    *(f32x4*)(out + idx) = o;
}

// ---------------------------------------------------------------------------
extern "C" void kernel_launch(void* const* d_in, const int* in_sizes, int n_in,
                              void* d_out, int out_size, void* d_ws, size_t ws_size,
                              hipStream_t stream) {
    const float* text = (const float*)d_in[0];
    const float* img  = (const float*)d_in[1];
    const float* i1_w = (const float*)d_in[4];
    const float* a1_w = (const float*)d_in[5];
    const float* t2_w = (const float*)d_in[7];
    const float* a2_w = (const float*)d_in[10];
    const float* gt_w = (const float*)d_in[12];
    const float* gt_b = (const float*)d_in[13];
    const float* gi_w = (const float*)d_in[14];
    const float* gi_b = (const float*)d_in[15];
    const float* gg_w = (const float*)d_in[16];
    const float* gg_b = (const float*)d_in[17];
    const float* ft_w = (const float*)d_in[18];
    const float* fm_w = (const float*)d_in[19];
    const float* fm_b = (const float*)d_in[20];
    const float* fg_w = (const float*)d_in[21];
    const float* fg_b = (const float*)d_in[22];
    const float* fr_w = (const float*)d_in[23];
    const float* fr_b = (const float*)d_in[24];
    float* out = (float*)d_out;

    // ---- scratch inside d_out (all uses precede out_kernel) ----
    float* sc_ = out;
    float* i_part  = sc_;                 // 1664*12 = 19968 (cap 38400)
    float* k_part  = sc_ + 38400;         // 16384*12 = 196608 (cap 393216)
    float* i_sc    = sc_ + 431616;        // 1568
    float* k_sc    = sc_ + 433216;        // 16384
    float* aimg    = sc_ + 449600;        // 24576
    float* v_f     = sc_ + 498752;        // 768
    float* v_m     = sc_ + 499520;        // 768
    float* c_m     = sc_ + 500288;        // 1 (+pad)
    float* ws_part = sc_ + 500352;        // 98304
    float* ni      = sc_ + 598656;        // 24576
    float* nt      = sc_ + 623232;        // 24576
    bf16* text_bf  = (bf16*)(sc_ + 672384);    // 12.58M bf16
    bf16* img_bf   = (bf16*)(sc_ + 6963840);   // 1204224 bf16
    bf16* wt_t     = (bf16*)(sc_ + 7565952);   // 589824 bf16 (also absorbs img OOB reads)
    bf16* wt_i     = (bf16*)(sc_ + 7860864);   // 589824 bf16 (ends 8155776 < 12.58M)

    // ---- ws holds only what out_kernel reads ----
    float* ws    = (float*)d_ws;
    float* s_txt = ws;                    // 16384
    float* s_mm  = ws + 16384;            // 32 (+pad)
    float* T     = ws + 16448;            // 24576

    // 0. fused prep: rank-1 collapses + img->bf16 + weight transposes
    prep_misc<<<dim3(385 + 588 + 288), dim3(256), 0, stream>>>(
        ft_w, fm_w, fm_b, fg_w, v_f, v_m, c_m, img, img_bf, t2_w, i1_w, wt_t, wt_i);
    // 0b. text fp32 -> bf16 + s_txt (needs v_f)
    prep_text<<<dim3(MT / 4), dim3(256), 0, stream>>>(text, v_f, text_bf, s_txt);
    // 1/2. merged score GEMMs (BK=64, single-buffer) + fused reduce+softmax
    gemm2<<<dim3(NWG), dim3(256), 0, stream>>>(
        text_bf, wt_t, a2_w + HD, k_part, img_bf, wt_i, a1_w + HD, i_part);
    red_soft<<<dim3(2 * BD), dim3(256), 0, stream>>>(k_part, i_part, k_sc, i_sc);
    // 6/7. attended rows (s-independent -> one row per batch)
    wsum_both<<<dim3(96 + 384), dim3(256), 0, stream>>>(
        i_sc, img, aimg, k_sc, text_bf, ws_part);
    // 8. GMF: ni/nt GEMV, then fused gate+T
    ni_nt_kernel<<<dim3(BD, HD / 64, 2), dim3(256), 0, stream>>>(
        aimg, ws_part, gi_w, gi_b, gt_w, gt_b, ni, nt);
    gateT<<<dim3(BD, HD / 64), dim3(256), 0, stream>>>(
        ni, nt, gg_w, gg_b, v_m, c_m, fg_b, fr_w, fr_b, T, s_mm);
    // 9. output (reads ws only; overwrites all of d_out)
    out_kernel<<<dim3((MT * HD / 4) / 256), dim3(256), 0, stream>>>(s_txt, s_mm, T, out);
}